// Round 8
// baseline (133.074 us; speedup 1.0000x reference)
//
#include <hip/hip_runtime.h>
#include <hip/hip_bf16.h>
#include <stdint.h>

#define N 8192
#define D 512
#define TILE 128
#define BK 64
#define NKC (D / BK)                  // 8 K-chunks
#define NTB (N / TILE)                // 64 tile-rows (= #slices)
#define NBLK (NTB * (NTB + 1) / 2)    // 2080 upper-tri blocks
#define PANEL_BYTES (TILE * D)        // 65536 B per 128-row fp8 panel
#define KCHUNK_BYTES (TILE * BK)      // 8192 B per staged fp8 tile

typedef long long i64;
typedef __attribute__((ext_vector_type(4))) float f32x4;

// async global->LDS, 16B per lane; LDS dest = wave-uniform base + lane*16
__device__ __forceinline__ void gload_lds16(const void* gp, const void* lp) {
    auto g = (const __attribute__((address_space(1))) void*)(uintptr_t)gp;
    auto l = (__attribute__((address_space(3))) void*)(uintptr_t)lp;
    __builtin_amdgcn_global_load_lds(g, l, 16, 0, 0);
}

// Fn2 swizzled fp8 layout (R7, verified):
//   byte(p, kc, ks, q, lr) = p*65536 + kc*8192 + ks*4096 + q*1024 + lr*8
// values = fp8_e4m3(16 * normalized_row)
__global__ void cc_normalize(const float* __restrict__ F, uint8_t* __restrict__ Fn2,
                             float* __restrict__ out) {
    if (blockIdx.x == 0 && threadIdx.x == 0) out[0] = 0.0f;
    const int row  = blockIdx.x * 4 + (threadIdx.x >> 6);
    const int lane = threadIdx.x & 63;
    const float* p = F + (size_t)row * D + lane * 8;
    float4 a = *(const float4*)p;
    float4 b = *(const float4*)(p + 4);
    float ss = a.x*a.x + a.y*a.y + a.z*a.z + a.w*a.w
             + b.x*b.x + b.y*b.y + b.z*b.z + b.w*b.w;
    #pragma unroll
    for (int m = 32; m; m >>= 1) ss += __shfl_xor(ss, m, 64);
    const float inv = 16.0f / fmaxf(sqrtf(ss), 1e-12f);
    int lo = 0, hi = 0;
    lo = __builtin_amdgcn_cvt_pk_fp8_f32(a.x*inv, a.y*inv, lo, false);
    lo = __builtin_amdgcn_cvt_pk_fp8_f32(a.z*inv, a.w*inv, lo, true);
    hi = __builtin_amdgcn_cvt_pk_fp8_f32(b.x*inv, b.y*inv, hi, false);
    hi = __builtin_amdgcn_cvt_pk_fp8_f32(b.z*inv, b.w*inv, hi, true);
    const size_t idx = (size_t)(row >> 7) * PANEL_BYTES + (size_t)lane * 1024 + (row & 127) * 8;
    *(int2*)(Fn2 + idx) = make_int2(lo, hi);
}

// 512 threads = 8 waves (4x2 grid, 32x64 wave-tile). LDS double-buffer,
// single barrier per K-step, fp8 MFMA. No atomics/fences (R6 scheme).
// Pair-row XCD swizzle: xcd = bi&7 owns 4 row-pairs (p, 63-p), 65 tiles each
// -> resident blocks on one XCD share A-panels + a contiguous B window (L2-hot).
__global__ __launch_bounds__(512, 6)
void cc_gemm(const uint8_t* __restrict__ Fn2, const int* __restrict__ cl,
             float* __restrict__ Pt, float* __restrict__ Pp) {
    __shared__ __align__(16) uint8_t As[2][KCHUNK_BYTES];   // 2 x 8 KB
    __shared__ __align__(16) uint8_t Bs[2][KCHUNK_BYTES];   // 2 x 8 KB
    __shared__ int crow[TILE], ccol[TILE];
    __shared__ float rsum[2][TILE][2];   // [wc][row][te,tp]   2 KB
    __shared__ float csum[4][TILE][2];   // [wr][col][te,tp]   4 KB

    const int tid  = threadIdx.x;
    const int wave = tid >> 6;
    const int lane = tid & 63;

    // pair-row XCD swizzle decode
    const int xcd = blockIdx.x & 7;
    const int s   = blockIdx.x >> 3;          // 0..259
    const int p   = xcd * 4 + s / 65;         // pair id 0..31, rows (p, 63-p)
    const int j   = s % 65;
    int bm, bn;
    if (j < NTB - p) { bm = p;          bn = p + j; }
    else             { bm = NTB - 1 - p; bn = bm + (j - (NTB - p)); }
    const bool diag = (bm == bn);

    if (tid < TILE)                         crow[tid]        = cl[bm * TILE + tid];
    else if (tid < 2 * TILE)                ccol[tid - TILE] = cl[bn * TILE + (tid - TILE)];

    const int wr = wave >> 1, wc = wave & 1;    // 4x2 wave grid, 32x64 each
    const int q   = lane >> 4;
    const int n15 = lane & 15;

    f32x4 acc[2][4];
    #pragma unroll
    for (int t = 0; t < 2; ++t)
        #pragma unroll
        for (int u = 0; u < 4; ++u) acc[t][u] = (f32x4)(0.0f);

    const uint8_t* Ag = Fn2 + (size_t)bm * PANEL_BYTES;
    const uint8_t* Bg = Fn2 + (size_t)bn * PANEL_BYTES;

    // prologue: stage kc=0 into buffer 0 (wave w: A-chunk w + B-chunk w, 1 KB each)
    gload_lds16(Ag + wave * 1024 + lane * 16, &As[0][wave * 1024]);
    gload_lds16(Bg + wave * 1024 + lane * 16, &Bs[0][wave * 1024]);

    for (int kc = 0; kc < NKC; ++kc) {
        const int b = kc & 1;
        __syncthreads();   // drains own vmcnt (stage issued one full phase ago)
        if (kc + 1 < NKC) {
            const uint8_t* ga = Ag + (kc + 1) * KCHUNK_BYTES;
            const uint8_t* gb = Bg + (kc + 1) * KCHUNK_BYTES;
            gload_lds16(ga + wave * 1024 + lane * 16, &As[b ^ 1][wave * 1024]);
            gload_lds16(gb + wave * 1024 + lane * 16, &Bs[b ^ 1][wave * 1024]);
        }
        #pragma unroll
        for (int ks = 0; ks < 2; ++ks) {
            const int base = ks * 4096 + q * 1024 + n15 * 8;
            i64 af[2], bfr[4];
            #pragma unroll
            for (int t = 0; t < 2; ++t)
                af[t] = *(const i64*)&As[b][base + (wr * 32 + t * 16) * 8];
            #pragma unroll
            for (int u = 0; u < 4; ++u)
                bfr[u] = *(const i64*)&Bs[b][base + (wc * 64 + u * 16) * 8];
            #pragma unroll
            for (int t = 0; t < 2; ++t)
                #pragma unroll
                for (int u = 0; u < 4; ++u)
                    acc[t][u] = __builtin_amdgcn_mfma_f32_16x16x32_fp8_fp8(af[t], bfr[u], acc[t][u], 0, 0, 0);
        }
    }

    // epilogue: sim = dot/256; e = exp2(dot * 10*log2(e)/256)
    const float SC = 0.05635527503472514f;
    int cc[4];
    #pragma unroll
    for (int u = 0; u < 4; ++u) cc[u] = ccol[wc * 64 + u * 16 + n15];

    float ce[4] = {0.f, 0.f, 0.f, 0.f};
    float cp[4] = {0.f, 0.f, 0.f, 0.f};

    #pragma unroll
    for (int t = 0; t < 2; ++t) {
        #pragma unroll
        for (int r = 0; r < 4; ++r) {
            const int lr  = wr * 32 + t * 16 + q * 4 + r;
            const int myc = crow[lr];
            float te = 0.0f, tp = 0.0f;
            #pragma unroll
            for (int u = 0; u < 4; ++u) {
                const float e  = exp2f(acc[t][u][r] * SC);
                const float ep = (cc[u] == myc) ? e : 0.0f;
                te += e;  tp += ep;
                ce[u] += e;  cp[u] += ep;
            }
            #pragma unroll
            for (int m = 1; m < 16; m <<= 1) {
                te += __shfl_xor(te, m, 64);
                tp += __shfl_xor(tp, m, 64);
            }
            if (n15 == 0) { rsum[wc][lr][0] = te; rsum[wc][lr][1] = tp; }
        }
    }

    if (!diag) {
        #pragma unroll
        for (int u = 0; u < 4; ++u) {
            float e = ce[u], p2 = cp[u];
            e += __shfl_xor(e, 16, 64);  p2 += __shfl_xor(p2, 16, 64);
            e += __shfl_xor(e, 32, 64);  p2 += __shfl_xor(p2, 32, 64);
            if (lane < 16) {
                const int lc = wc * 64 + u * 16 + n15;
                csum[wr][lc][0] = e;  csum[wr][lc][1] = p2;
            }
        }
    }

    __syncthreads();
    if (tid < TILE) {
        const float te = rsum[0][tid][0] + rsum[1][tid][0];
        const float tp = rsum[0][tid][1] + rsum[1][tid][1];
        const size_t o = (size_t)bn * N + bm * TILE + tid;
        Pt[o] = te;  Pp[o] = tp;
    } else if (tid < 2 * TILE && !diag) {
        const int c = tid - TILE;
        const float te = csum[0][c][0] + csum[1][c][0] + csum[2][c][0] + csum[3][c][0];
        const float tp = csum[0][c][1] + csum[1][c][1] + csum[2][c][1] + csum[3][c][1];
        const size_t o = (size_t)bm * N + bn * TILE + c;
        Pt[o] = te;  Pp[o] = tp;
    }
}

// 32 blocks x 256: row i sums its 64 slices, loss, block-reduce, atomicAdd out
__global__ void cc_finalize(const float* __restrict__ Pt, const float* __restrict__ Pp,
                            float* __restrict__ out) {
    __shared__ float red[4];
    const int i = blockIdx.x * 256 + threadIdx.x;
    float tv = 0.0f, pv = 0.0f;
    #pragma unroll 8
    for (int s = 0; s < NTB; ++s) {
        tv += Pt[(size_t)s * N + i];
        pv += Pp[(size_t)s * N + i];
    }
    float l = __logf(tv + 1e-8f) - __logf(pv);
    #pragma unroll
    for (int m = 32; m; m >>= 1) l += __shfl_xor(l, m, 64);
    const int wv = threadIdx.x >> 6, lane = threadIdx.x & 63;
    if (lane == 0) red[wv] = l;
    __syncthreads();
    if (threadIdx.x == 0) atomicAdd(out, red[0] + red[1] + red[2] + red[3]);
}

extern "C" void kernel_launch(void* const* d_in, const int* in_sizes, int n_in,
                              void* d_out, int out_size, void* d_ws, size_t ws_size,
                              hipStream_t stream) {
    const float* F  = (const float*)d_in[0];
    const int*   cl = (const int*)d_in[1];
    float* out = (float*)d_out;

    uint8_t* Fn2 = (uint8_t*)d_ws;                               // 4 MB fp8 swizzled
    float* Pt  = (float*)((char*)d_ws + (size_t)N * D);          // 2 MB
    float* Pp  = Pt + (size_t)NTB * N;                           // 2 MB

    cc_normalize<<<N / 4, 256, 0, stream>>>(F, Fn2, out);
    cc_gemm<<<NBLK, 512, 0, stream>>>(Fn2, cl, Pt, Pp);
    cc_finalize<<<N / 256, 256, 0, stream>>>(Pt, Pp, out);
}